// Round 3
// baseline (1264.500 us; speedup 1.0000x reference)
//
#include <hip/hip_runtime.h>

typedef short v8s __attribute__((ext_vector_type(8)));
typedef float v4f __attribute__((ext_vector_type(4)));

#define BMT 128
#define BNT 128
#define BKT 32

__device__ __forceinline__ unsigned short f2bf(float f) {
    unsigned int u = __float_as_uint(f);
    u += 0x7fff + ((u >> 16) & 1);   // RNE
    return (unsigned short)(u >> 16);
}
__device__ __forceinline__ float bf2f(unsigned short h) {
    return __uint_as_float(((unsigned int)h) << 16);
}

union U128 { unsigned short s[8]; uint4 v; };

// async 16B global -> LDS (wave-uniform LDS base + lane*16 implicit)
__device__ __forceinline__ void gld16(const unsigned short* g, unsigned short* l) {
    __builtin_amdgcn_global_load_lds((const __attribute__((address_space(1))) void*)g,
                                     (__attribute__((address_space(3))) void*)l, 16, 0, 0);
}

// ---------------------------------------------------------------------------
__global__ __launch_bounds__(256) void split_pair(const float* __restrict__ x,
                                                  unsigned short* __restrict__ oh,
                                                  unsigned short* __restrict__ ol, int n4) {
    int i = blockIdx.x * 256 + threadIdx.x;
    if (i < n4) {
        float4 f = ((const float4*)x)[i];
        float fv[4] = {f.x, f.y, f.z, f.w};
        ushort4 h, l;
        unsigned short* hp = (unsigned short*)&h;
        unsigned short* lp = (unsigned short*)&l;
#pragma unroll
        for (int j = 0; j < 4; ++j) {
            unsigned short hh = f2bf(fv[j]);
            hp[j] = hh;
            lp[j] = f2bf(fv[j] - bf2f(hh));
        }
        ((ushort4*)oh)[i] = h;
        ((ushort4*)ol)[i] = l;
    }
}

// split + transpose: W fp32 [R][C] -> WT hi/lo bf16 [C][R]
__global__ __launch_bounds__(256) void tsplit(const float* __restrict__ W,
                                              unsigned short* __restrict__ th,
                                              unsigned short* __restrict__ tl, int R, int C) {
    int e = blockIdx.x * 256 + threadIdx.x;
    if (e < R * C) {
        int k = e / C, n = e - k * C;
        float w = W[e];
        unsigned short h = f2bf(w);
        size_t o = (size_t)n * R + k;
        th[o] = h;
        tl[o] = f2bf(w - bf2f(h));
    }
}

// ---------------------------------------------------------------------------
// 128x128x32 split-bf16 GEMM.
// AMODE: 0 = pre-split bf16 hi/lo [M][K] via global_load_lds (swizzled LDS)
//        1 = fp32 source, split in-kernel (padded LDS)          [adj fallback]
// BMODE: 0 = pre-split k-contiguous [N][ldb] via global_load_lds (swizzled)
//        1 = gather from normal hi/lo [K][N] (padded LDS)       [x for agg1]
// ACT: 0 none/no bias, 1 bias+relu, 2 bias+prelu
// WRT: also write transposed output HT[zb][Nout][1024] via LDS transpose
template <int ACT, bool TWO, int AMODE, int BMODE, bool WRT>
__global__ __launch_bounds__(256) void gemm128(
    const void* a1a, const void* a1b,
    const unsigned short* __restrict__ a2h, const unsigned short* __restrict__ a2l,
    int K1, int K2,
    const unsigned short* __restrict__ bh_, const unsigned short* __restrict__ bl_, int ldb,
    const float* __restrict__ bias, const float* __restrict__ alpha,
    unsigned short* __restrict__ oh, unsigned short* __restrict__ ol, int Nout,
    unsigned short* __restrict__ hth, unsigned short* __restrict__ htl,
    size_t aZStride, size_t bZStride, int cZRows)
{
    constexpr int LA = (AMODE == 0) ? 32 : 40;
    constexpr int LB = (BMODE == 0) ? 32 : 40;
    constexpr int STAGE = 2 * (BMT * LA + BNT * LB) * 2;
    constexpr int TRANS = WRT ? 64 * 132 * 4 : 0;
    constexpr int SMEM = STAGE > TRANS ? STAGE : TRANS;
    __shared__ __align__(16) char smem[SMEM];
    unsigned short* Ash = (unsigned short*)smem;
    unsigned short* Asl = Ash + BMT * LA;
    unsigned short* Bsh = Asl + BMT * LA;
    unsigned short* Bsl = Bsh + BNT * LB;
    unsigned int* tbuf = (unsigned int*)smem;

    const int t = threadIdx.x;
    const int lane = t & 63, wave = t >> 6;
    const int wm = wave >> 1, wn = wave & 1;
    const int l15 = lane & 15, quad = lane >> 4;
    const int zb = blockIdx.z;
    const int n0 = blockIdx.x * BNT;
    const int m0 = blockIdx.y * BMT;

    const unsigned short* bhz = bh_ + (size_t)zb * bZStride;
    const unsigned short* blz = bl_ + (size_t)zb * bZStride;

    v4f acc[4][4] = {};

    const int nch = TWO ? 2 : 1;
    for (int ch = 0; ch < nch; ++ch) {
        const int K = (TWO && ch) ? K2 : K1;
        const int kr0 = (TWO && ch) ? K1 : 0;
        const unsigned short* ah = nullptr;
        const unsigned short* al = nullptr;
        const float* af = nullptr;
        if constexpr (AMODE == 0) {
            ah = (ch ? a2h : (const unsigned short*)a1a) + (size_t)zb * aZStride;
            al = (ch ? a2l : (const unsigned short*)a1b) + (size_t)zb * aZStride;
        } else {
            af = (const float*)a1a + (size_t)zb * aZStride;
        }

        for (int kk = 0; kk < K; kk += BKT) {
            __syncthreads();
            // ---- stage A
            if constexpr (AMODE == 0) {
#pragma unroll
                for (int i = 0; i < 2; ++i) {
                    int s = i * 256 + t;
                    int row = s >> 2;
                    int cg = (s & 3) ^ ((s >> 3) & 3);           // chunk swizzle
                    size_t go = (size_t)(m0 + row) * K + kk + cg * 8;
                    int ls = (i * 256 + (t & ~63)) * 8;          // wave-uniform base
                    gld16(ah + go, &Ash[ls]);
                    gld16(al + go, &Asl[ls]);
                }
            } else {
#pragma unroll
                for (int i = 0; i < 2; ++i) {
                    int cid = i * 256 + t;
                    int row = cid >> 2, c = cid & 3;
                    const float* src = af + (size_t)(m0 + row) * K + kk + c * 8;
                    float4 f0 = *(const float4*)src;
                    float4 f1 = *(const float4*)(src + 4);
                    float fv[8] = {f0.x, f0.y, f0.z, f0.w, f1.x, f1.y, f1.z, f1.w};
                    U128 uh, ul;
#pragma unroll
                    for (int j = 0; j < 8; ++j) {
                        unsigned short h = f2bf(fv[j]);
                        uh.s[j] = h;
                        ul.s[j] = f2bf(fv[j] - bf2f(h));
                    }
                    *(uint4*)&Ash[row * LA + c * 8] = uh.v;
                    *(uint4*)&Asl[row * LA + c * 8] = ul.v;
                }
            }
            // ---- stage B
            if constexpr (BMODE == 0) {
#pragma unroll
                for (int i = 0; i < 2; ++i) {
                    int s = i * 256 + t;
                    int row = s >> 2;
                    int cg = (s & 3) ^ ((s >> 3) & 3);
                    size_t go = (size_t)(n0 + row) * ldb + kr0 + kk + cg * 8;
                    int ls = (i * 256 + (t & ~63)) * 8;
                    gld16(bhz + go, &Bsh[ls]);
                    gld16(blz + go, &Bsl[ls]);
                }
            } else {
                int bn = t & 127, kb = (t >> 7) * 16;
                U128 h0, h1, l0, l1;
#pragma unroll
                for (int j = 0; j < 8; ++j) {
                    size_t o = (size_t)(kk + kb + j) * ldb + n0 + bn;
                    h0.s[j] = bhz[o];
                    l0.s[j] = blz[o];
                }
#pragma unroll
                for (int j = 0; j < 8; ++j) {
                    size_t o = (size_t)(kk + kb + 8 + j) * ldb + n0 + bn;
                    h1.s[j] = bhz[o];
                    l1.s[j] = blz[o];
                }
                *(uint4*)&Bsh[bn * LB + kb] = h0.v;
                *(uint4*)&Bsh[bn * LB + kb + 8] = h1.v;
                *(uint4*)&Bsl[bn * LB + kb] = l0.v;
                *(uint4*)&Bsl[bn * LB + kb + 8] = l1.v;
            }
            __syncthreads();
            // ---- compute
            v8s ahf[4], alf[4];
#pragma unroll
            for (int mi = 0; mi < 4; ++mi) {
                int row = wm * 64 + mi * 16 + l15;
                int off;
                if constexpr (AMODE == 0) off = row * LA + ((quad ^ ((row >> 1) & 3)) * 8);
                else                      off = row * LA + quad * 8;
                ahf[mi] = *(const v8s*)&Ash[off];
                alf[mi] = *(const v8s*)&Asl[off];
            }
#pragma unroll
            for (int ni = 0; ni < 4; ++ni) {
                int row = wn * 64 + ni * 16 + l15;
                int off;
                if constexpr (BMODE == 0) off = row * LB + ((quad ^ ((row >> 1) & 3)) * 8);
                else                      off = row * LB + quad * 8;
                v8s bhf = *(const v8s*)&Bsh[off];
                v8s blf = *(const v8s*)&Bsl[off];
#pragma unroll
                for (int mi = 0; mi < 4; ++mi) {
                    acc[mi][ni] = __builtin_amdgcn_mfma_f32_16x16x32_bf16(ahf[mi], bhf, acc[mi][ni], 0, 0, 0);
                    acc[mi][ni] = __builtin_amdgcn_mfma_f32_16x16x32_bf16(ahf[mi], blf, acc[mi][ni], 0, 0, 0);
                    acc[mi][ni] = __builtin_amdgcn_mfma_f32_16x16x32_bf16(alf[mi], bhf, acc[mi][ni], 0, 0, 0);
                }
            }
        }
    }

    // ---- fold bias + activation into acc
#pragma unroll
    for (int ni = 0; ni < 4; ++ni) {
        int n = n0 + wn * 64 + ni * 16 + l15;
        float bv = (ACT > 0) ? bias[n] : 0.f;
        float av = (ACT == 2) ? alpha[n] : 0.f;
#pragma unroll
        for (int mi = 0; mi < 4; ++mi)
#pragma unroll
            for (int r = 0; r < 4; ++r) {
                float v = acc[mi][ni][r] + bv;
                if (ACT == 1) v = v > 0.f ? v : 0.f;
                if (ACT == 2) v = v > 0.f ? v : av * v;
                acc[mi][ni][r] = v;
            }
    }

    // ---- normal-layout split store
    const size_t crow0 = (size_t)zb * cZRows + m0;
#pragma unroll
    for (int ni = 0; ni < 4; ++ni) {
        int n = n0 + wn * 64 + ni * 16 + l15;
#pragma unroll
        for (int mi = 0; mi < 4; ++mi)
#pragma unroll
            for (int r = 0; r < 4; ++r) {
                int m = wm * 64 + mi * 16 + quad * 4 + r;
                float v = acc[mi][ni][r];
                size_t o = (crow0 + m) * (size_t)Nout + n;
                unsigned short h = f2bf(v);
                oh[o] = h;
                ol[o] = f2bf(v - bf2f(h));
            }
    }

    // ---- transposed write HT[zb][Nout][1024] via LDS transpose
    if constexpr (WRT) {
        const int zbT = m0 >> 10;
        const int mloc0 = m0 & 1023;
#pragma unroll
        for (int half = 0; half < 2; ++half) {
            __syncthreads();
            if (wn == half) {
#pragma unroll
                for (int ni = 0; ni < 4; ++ni)
#pragma unroll
                    for (int mi = 0; mi < 4; ++mi) {
                        int nl = ni * 16 + l15;
                        int mg = wm * 16 + mi * 4 + quad;
                        uint4 u;
                        unsigned int* up = (unsigned int*)&u;
#pragma unroll
                        for (int r = 0; r < 4; ++r) {
                            float v = acc[mi][ni][r];
                            unsigned short hs = f2bf(v);
                            unsigned short ls = f2bf(v - bf2f(hs));
                            up[r] = ((unsigned int)hs << 16) | ls;
                        }
                        *(uint4*)&tbuf[nl * 132 + mg * 4] = u;
                    }
            }
            __syncthreads();
#pragma unroll
            for (int pass = 0; pass < 8; ++pass) {
                int row = pass * 8 + (t >> 5), c4 = t & 31;
                uint4 u = *(const uint4*)&tbuf[row * 132 + c4 * 4];
                ushort4 hh, ll;
                hh.x = u.x >> 16; hh.y = u.y >> 16; hh.z = u.z >> 16; hh.w = u.w >> 16;
                ll.x = u.x & 0xffff; ll.y = u.y & 0xffff; ll.z = u.z & 0xffff; ll.w = u.w & 0xffff;
                size_t ob = (size_t)zbT * Nout * 1024 + (size_t)(n0 + half * 64 + row) * 1024
                          + mloc0 + c4 * 4;
                *(ushort4*)(hth + ob) = hh;
                *(ushort4*)(htl + ob) = ll;
            }
        }
    }
}

// ---------------------------------------------------------------------------
__global__ __launch_bounds__(256) void final_gemm(const unsigned short* __restrict__ hh,
                                                  const unsigned short* __restrict__ hl,
                                                  const float* __restrict__ W,
                                                  const float* __restrict__ bias,
                                                  float* __restrict__ out) {
    const int t = threadIdx.x;
    const int m = blockIdx.x * 64 + (t >> 2);
    const int kq = (t & 3) * 64;
    const unsigned short* ph = hh + (size_t)m * 256 + kq;
    const unsigned short* pl = hl + (size_t)m * 256 + kq;
    float a0 = 0.f, a1 = 0.f;
#pragma unroll
    for (int i = 0; i < 8; ++i) {
        uint4 vh = *(const uint4*)(ph + i * 8);
        uint4 vl = *(const uint4*)(pl + i * 8);
        const unsigned short* sh = (const unsigned short*)&vh;
        const unsigned short* sl = (const unsigned short*)&vl;
#pragma unroll
        for (int j = 0; j < 8; ++j) {
            int k = kq + i * 8 + j;
            float h = bf2f(sh[j]) + bf2f(sl[j]);
            a0 += h * W[k * 2];
            a1 += h * W[k * 2 + 1];
        }
    }
    a0 += __shfl_down(a0, 2); a0 += __shfl_down(a0, 1);
    a1 += __shfl_down(a1, 2); a1 += __shfl_down(a1, 1);
    if ((t & 3) == 0) {
        out[(size_t)m * 2] = a0 + bias[0];
        out[(size_t)m * 2 + 1] = a1 + bias[1];
    }
}

// ---------------------------------------------------------------------------
extern "C" void kernel_launch(void* const* d_in, const int* in_sizes, int n_in,
                              void* d_out, int out_size, void* d_ws, size_t ws_size,
                              hipStream_t stream) {
    const float* x   = (const float*)d_in[0];
    const float* adj = (const float*)d_in[1];
    const float* W1  = (const float*)d_in[2];
    const float* b1  = (const float*)d_in[3];
    const float* W2  = (const float*)d_in[4];
    const float* b2  = (const float*)d_in[5];
    const float* W3  = (const float*)d_in[6];
    const float* b3  = (const float*)d_in[7];
    const float* W4  = (const float*)d_in[8];
    const float* b4  = (const float*)d_in[9];
    const float* cW1 = (const float*)d_in[10];
    const float* cb1 = (const float*)d_in[11];
    const float* alp = (const float*)d_in[12];
    const float* cW2 = (const float*)d_in[13];
    const float* cb2 = (const float*)d_in[14];
    float* out = (float*)d_out;

    const size_t P = 32768ull * 512;
    const size_t WT_TOT = 1245184;
    const size_t ADJ = 32ull * 1024 * 1024;

    unsigned short* N1h = (unsigned short*)d_ws;
    unsigned short* N1l = N1h + P;
    unsigned short* N2h = N1l + P;
    unsigned short* N2l = N2h + P;
    unsigned short* N3h = N2l + P;
    unsigned short* N3l = N3h + P;
    unsigned short* Th  = N3l + P;
    unsigned short* Tl  = Th + P;
    unsigned short* WTh = Tl + P;
    unsigned short* WTl = WTh + WT_TOT;
    unsigned short* SAh = WTl + WT_TOT;
    unsigned short* SAl = SAh + ADJ;

    const size_t o1 = 0, o2 = 262144, o3 = 786432, o4 = 1048576, o5 = 1179648;
    const bool preAdj = ws_size >= (8 * P + 2 * WT_TOT + 2 * ADJ) * sizeof(unsigned short);

    dim3 blk(256);

    split_pair<<<8192, blk, 0, stream>>>(x, N1h, N1l, (int)(32ull * 1024 * 256 / 4));
    tsplit<<<1024, blk, 0, stream>>>(W1,  WTh + o1, WTl + o1, 512, 512);
    tsplit<<<2048, blk, 0, stream>>>(W2,  WTh + o2, WTl + o2, 1024, 512);
    tsplit<<<1024, blk, 0, stream>>>(W3,  WTh + o3, WTl + o3, 1024, 256);
    tsplit<<<512,  blk, 0, stream>>>(W4,  WTh + o4, WTl + o4, 512, 256);
    tsplit<<<256,  blk, 0, stream>>>(cW1, WTh + o5, WTl + o5, 256, 256);
    if (preAdj)
        split_pair<<<32768, blk, 0, stream>>>(adj, SAh, SAl, (int)(ADJ / 4));

    // agg1 = adj @ x (d=256) -> N2   [B gathered from normal x split]
    if (preAdj)
        gemm128<0, false, 0, 1, false><<<dim3(2, 8, 32), blk, 0, stream>>>(
            SAh, SAl, nullptr, nullptr, 1024, 0, N1h, N1l, 256, nullptr, nullptr,
            N2h, N2l, 256, nullptr, nullptr, (size_t)1 << 20, 1024ull * 256, 1024);
    else
        gemm128<0, false, 1, 1, false><<<dim3(2, 8, 32), blk, 0, stream>>>(
            adj, nullptr, nullptr, nullptr, 1024, 0, N1h, N1l, 256, nullptr, nullptr,
            N2h, N2l, 256, nullptr, nullptr, (size_t)1 << 20, 1024ull * 256, 1024);
    // dense1 (N=512) -> N3, writes H1T -> T
    gemm128<1, true, 0, 0, true><<<dim3(4, 256, 1), blk, 0, stream>>>(
        N1h, N1l, N2h, N2l, 256, 256, WTh + o1, WTl + o1, 512, b1, nullptr,
        N3h, N3l, 512, Th, Tl, 0, 0, 0);
    // agg2 = adj @ H1 (d=512) -> N1  [B from H1T, all gld16]
    if (preAdj)
        gemm128<0, false, 0, 0, false><<<dim3(4, 8, 32), blk, 0, stream>>>(
            SAh, SAl, nullptr, nullptr, 1024, 0, Th, Tl, 1024, nullptr, nullptr,
            N1h, N1l, 512, nullptr, nullptr, (size_t)1 << 20, 512ull * 1024, 1024);
    else
        gemm128<0, false, 1, 0, false><<<dim3(4, 8, 32), blk, 0, stream>>>(
            adj, nullptr, nullptr, nullptr, 1024, 0, Th, Tl, 1024, nullptr, nullptr,
            N1h, N1l, 512, nullptr, nullptr, (size_t)1 << 20, 512ull * 1024, 1024);
    // dense2 (N=512) -> N2, writes H2T -> T
    gemm128<1, true, 0, 0, true><<<dim3(4, 256, 1), blk, 0, stream>>>(
        N3h, N3l, N1h, N1l, 512, 512, WTh + o2, WTl + o2, 1024, b2, nullptr,
        N2h, N2l, 512, Th, Tl, 0, 0, 0);
    // agg3 = adj @ H2 (d=512) -> N1
    if (preAdj)
        gemm128<0, false, 0, 0, false><<<dim3(4, 8, 32), blk, 0, stream>>>(
            SAh, SAl, nullptr, nullptr, 1024, 0, Th, Tl, 1024, nullptr, nullptr,
            N1h, N1l, 512, nullptr, nullptr, (size_t)1 << 20, 512ull * 1024, 1024);
    else
        gemm128<0, false, 1, 0, false><<<dim3(4, 8, 32), blk, 0, stream>>>(
            adj, nullptr, nullptr, nullptr, 1024, 0, Th, Tl, 1024, nullptr, nullptr,
            N1h, N1l, 512, nullptr, nullptr, (size_t)1 << 20, 512ull * 1024, 1024);
    // dense3 (N=256) -> N3, writes H3T -> T
    gemm128<1, true, 0, 0, true><<<dim3(2, 256, 1), blk, 0, stream>>>(
        N2h, N2l, N1h, N1l, 512, 512, WTh + o3, WTl + o3, 1024, b3, nullptr,
        N3h, N3l, 256, Th, Tl, 0, 0, 0);
    // agg4 = adj @ H3 (d=256) -> N1
    if (preAdj)
        gemm128<0, false, 0, 0, false><<<dim3(2, 8, 32), blk, 0, stream>>>(
            SAh, SAl, nullptr, nullptr, 1024, 0, Th, Tl, 1024, nullptr, nullptr,
            N1h, N1l, 256, nullptr, nullptr, (size_t)1 << 20, 256ull * 1024, 1024);
    else
        gemm128<0, false, 1, 0, false><<<dim3(2, 8, 32), blk, 0, stream>>>(
            adj, nullptr, nullptr, nullptr, 1024, 0, Th, Tl, 1024, nullptr, nullptr,
            N1h, N1l, 256, nullptr, nullptr, (size_t)1 << 20, 256ull * 1024, 1024);
    // dense4 (N=256) -> N2
    gemm128<1, true, 0, 0, false><<<dim3(2, 256, 1), blk, 0, stream>>>(
        N3h, N3l, N1h, N1l, 256, 256, WTh + o4, WTl + o4, 512, b4, nullptr,
        N2h, N2l, 256, nullptr, nullptr, 0, 0, 0);
    // cls1 = prelu(H4 @ cW1 + cb1) (N=256) -> N3
    gemm128<2, false, 0, 0, false><<<dim3(2, 256, 1), blk, 0, stream>>>(
        N2h, N2l, nullptr, nullptr, 256, 0, WTh + o5, WTl + o5, 256, cb1, alp,
        N3h, N3l, 256, nullptr, nullptr, 0, 0, 0);
    // final
    final_gemm<<<512, blk, 0, stream>>>(N3h, N3l, cW2, cb2, out);
}

// Round 4
// 1096.904 us; speedup vs baseline: 1.1528x; 1.1528x over previous
//
#include <hip/hip_runtime.h>

typedef short v8s __attribute__((ext_vector_type(8)));
typedef float v4f __attribute__((ext_vector_type(4)));

#define BMT 128
#define BNT 128
#define BKT 32

__device__ __forceinline__ unsigned short f2bf(float f) {
    unsigned int u = __float_as_uint(f);
    u += 0x7fff + ((u >> 16) & 1);   // RNE
    return (unsigned short)(u >> 16);
}
__device__ __forceinline__ float bf2f(unsigned short h) {
    return __uint_as_float(((unsigned int)h) << 16);
}

union U128 { unsigned short s[8]; uint4 v; };

// async 16B global -> LDS (wave-uniform LDS base + lane*16 implicit)
__device__ __forceinline__ void gld16(const unsigned short* g, unsigned short* l) {
    __builtin_amdgcn_global_load_lds((const __attribute__((address_space(1))) void*)g,
                                     (__attribute__((address_space(3))) void*)l, 16, 0, 0);
}

// ---------------------------------------------------------------------------
__global__ __launch_bounds__(256) void split_pair(const float* __restrict__ x,
                                                  unsigned short* __restrict__ oh,
                                                  unsigned short* __restrict__ ol, int n4) {
    int i = blockIdx.x * 256 + threadIdx.x;
    if (i < n4) {
        float4 f = ((const float4*)x)[i];
        float fv[4] = {f.x, f.y, f.z, f.w};
        ushort4 h, l;
        unsigned short* hp = (unsigned short*)&h;
        unsigned short* lp = (unsigned short*)&l;
#pragma unroll
        for (int j = 0; j < 4; ++j) {
            unsigned short hh = f2bf(fv[j]);
            hp[j] = hh;
            lp[j] = f2bf(fv[j] - bf2f(hh));
        }
        ((ushort4*)oh)[i] = h;
        ((ushort4*)ol)[i] = l;
    }
}

// split + transpose: W fp32 [R][C] -> WT hi/lo bf16 [C][R]
__global__ __launch_bounds__(256) void tsplit(const float* __restrict__ W,
                                              unsigned short* __restrict__ th,
                                              unsigned short* __restrict__ tl, int R, int C) {
    int e = blockIdx.x * 256 + threadIdx.x;
    if (e < R * C) {
        int k = e / C, n = e - k * C;
        float w = W[e];
        unsigned short h = f2bf(w);
        size_t o = (size_t)n * R + k;
        th[o] = h;
        tl[o] = f2bf(w - bf2f(h));
    }
}

// ---------------------------------------------------------------------------
// Transpose H [z*1024+node][d] (split hi/lo, or fp32 if F32) -> HT [z*d+f][1024]
// 64x64 tiles, packed hi|lo uint in LDS (pad 66), coalesced both sides.
template <bool F32>
__global__ __launch_bounds__(256) void transp(const void* __restrict__ srcA,
                                              const unsigned short* __restrict__ srcL,
                                              unsigned short* __restrict__ th,
                                              unsigned short* __restrict__ tl, int d) {
    __shared__ unsigned int lds[64 * 66];
    const int t = threadIdx.x;
    const int mt = blockIdx.x, ft = blockIdx.y, z = blockIdx.z;
    const int r = t >> 3, c8 = (t & 7) * 8;
#pragma unroll
    for (int half = 0; half < 2; ++half) {
        int rr = r + half * 32;
        size_t grow = (size_t)z * 1024 + mt * 64 + rr;
        unsigned int u[8];
        if constexpr (F32) {
            const float* xs = (const float*)srcA + grow * d + ft * 64 + c8;
            float4 f0 = *(const float4*)xs;
            float4 f1 = *(const float4*)(xs + 4);
            float fv[8] = {f0.x, f0.y, f0.z, f0.w, f1.x, f1.y, f1.z, f1.w};
#pragma unroll
            for (int j = 0; j < 8; ++j) {
                unsigned short hs = f2bf(fv[j]);
                unsigned short ls = f2bf(fv[j] - bf2f(hs));
                u[j] = ((unsigned int)hs << 16) | ls;
            }
        } else {
            const unsigned short* hp = (const unsigned short*)srcA + grow * d + ft * 64 + c8;
            const unsigned short* lp = srcL + grow * d + ft * 64 + c8;
            U128 uh, ul;
            uh.v = *(const uint4*)hp;
            ul.v = *(const uint4*)lp;
#pragma unroll
            for (int j = 0; j < 8; ++j)
                u[j] = ((unsigned int)uh.s[j] << 16) | ul.s[j];
        }
#pragma unroll
        for (int j = 0; j < 8; ++j)
            lds[rr * 66 + c8 + j] = u[j];
    }
    __syncthreads();
    const int f = t >> 3, m0 = (t & 7) * 8;
#pragma unroll
    for (int half = 0; half < 2; ++half) {
        int ff = f + half * 32;
        U128 uh, ul;
#pragma unroll
        for (int j = 0; j < 8; ++j) {
            unsigned int u = lds[(m0 + j) * 66 + ff];
            uh.s[j] = u >> 16;
            ul.s[j] = u & 0xffff;
        }
        size_t orow = ((size_t)z * d + ft * 64 + ff) * 1024 + mt * 64 + m0;
        *(uint4*)(th + orow) = uh.v;
        *(uint4*)(tl + orow) = ul.v;
    }
}

// ---------------------------------------------------------------------------
// 128x128x32 split-bf16 GEMM, 1-D swizzled grid (nblk n-blocks co-located per XCD).
// AMODE: 0 = pre-split bf16 hi/lo [M][K] via global_load_lds
//        1 = fp32 source, split in-kernel (padded LDS)   [adj fallback]
// B always pre-split k-contiguous [N][ldb] via global_load_lds.
// ACT: 0 none/no bias, 1 bias+relu, 2 bias+prelu
template <int ACT, bool TWO, int AMODE>
__global__ __launch_bounds__(256) void gemm128(
    const void* a1a, const void* a1b,
    const unsigned short* __restrict__ a2h, const unsigned short* __restrict__ a2l,
    int K1, int K2,
    const unsigned short* __restrict__ bh_, const unsigned short* __restrict__ bl_, int ldb,
    const float* __restrict__ bias, const float* __restrict__ alpha,
    unsigned short* __restrict__ oh, unsigned short* __restrict__ ol, int Nout,
    size_t aZStride, size_t bZStride, int cZRows,
    int nblk, int mBits)
{
    constexpr int LA = (AMODE == 0) ? 32 : 40;
    constexpr int LB = 32;
    __shared__ __align__(16) unsigned short Ash[BMT * LA], Asl[BMT * LA];
    __shared__ __align__(16) unsigned short Bsh[BNT * LB], Bsl[BNT * LB];

    const int t = threadIdx.x;
    const int lane = t & 63, wave = t >> 6;
    const int wm = wave >> 1, wn = wave & 1;
    const int l15 = lane & 15, quad = lane >> 4;

    // swizzled decode: n-blocks sharing an A-panel land on the same XCD
    const int bx = blockIdx.x;
    const int low3 = bx & 7, rest = bx >> 3;
    const int nIdx = rest % nblk, g = rest / nblk;
    const int grp = g * 8 + low3;
    const int m0 = (grp & ((1 << mBits) - 1)) * BMT;
    const int zb = grp >> mBits;
    const int n0 = nIdx * BNT;

    const unsigned short* bhz = bh_ + (size_t)zb * bZStride;
    const unsigned short* blz = bl_ + (size_t)zb * bZStride;

    v4f acc[4][4] = {};

    const int nch = TWO ? 2 : 1;
    for (int ch = 0; ch < nch; ++ch) {
        const int K = (TWO && ch) ? K2 : K1;
        const int kr0 = (TWO && ch) ? K1 : 0;
        const unsigned short* ah = nullptr;
        const unsigned short* al = nullptr;
        const float* af = nullptr;
        if constexpr (AMODE == 0) {
            ah = (ch ? a2h : (const unsigned short*)a1a) + (size_t)zb * aZStride;
            al = (ch ? a2l : (const unsigned short*)a1b) + (size_t)zb * aZStride;
        } else {
            af = (const float*)a1a + (size_t)zb * aZStride;
        }

        for (int kk = 0; kk < K; kk += BKT) {
            __syncthreads();
            // ---- stage A
            if constexpr (AMODE == 0) {
#pragma unroll
                for (int i = 0; i < 2; ++i) {
                    int s = i * 256 + t;
                    int row = s >> 2;
                    int cg = (s & 3) ^ ((s >> 3) & 3);           // chunk swizzle
                    size_t go = (size_t)(m0 + row) * K + kk + cg * 8;
                    int ls = (i * 256 + (t & ~63)) * 8;          // wave-uniform base
                    gld16(ah + go, &Ash[ls]);
                    gld16(al + go, &Asl[ls]);
                }
            } else {
#pragma unroll
                for (int i = 0; i < 2; ++i) {
                    int cid = i * 256 + t;
                    int row = cid >> 2, c = cid & 3;
                    const float* src = af + (size_t)(m0 + row) * K + kk + c * 8;
                    float4 f0 = *(const float4*)src;
                    float4 f1 = *(const float4*)(src + 4);
                    float fv[8] = {f0.x, f0.y, f0.z, f0.w, f1.x, f1.y, f1.z, f1.w};
                    U128 uh, ul;
#pragma unroll
                    for (int j = 0; j < 8; ++j) {
                        unsigned short h = f2bf(fv[j]);
                        uh.s[j] = h;
                        ul.s[j] = f2bf(fv[j] - bf2f(h));
                    }
                    *(uint4*)&Ash[row * LA + c * 8] = uh.v;
                    *(uint4*)&Asl[row * LA + c * 8] = ul.v;
                }
            }
            // ---- stage B (always gld16)
#pragma unroll
            for (int i = 0; i < 2; ++i) {
                int s = i * 256 + t;
                int row = s >> 2;
                int cg = (s & 3) ^ ((s >> 3) & 3);
                size_t go = (size_t)(n0 + row) * ldb + kr0 + kk + cg * 8;
                int ls = (i * 256 + (t & ~63)) * 8;
                gld16(bhz + go, &Bsh[ls]);
                gld16(blz + go, &Bsl[ls]);
            }
            __syncthreads();
            // ---- compute
            v8s ahf[4], alf[4];
#pragma unroll
            for (int mi = 0; mi < 4; ++mi) {
                int row = wm * 64 + mi * 16 + l15;
                int off;
                if constexpr (AMODE == 0) off = row * LA + ((quad ^ ((row >> 1) & 3)) * 8);
                else                      off = row * LA + quad * 8;
                ahf[mi] = *(const v8s*)&Ash[off];
                alf[mi] = *(const v8s*)&Asl[off];
            }
#pragma unroll
            for (int ni = 0; ni < 4; ++ni) {
                int row = wn * 64 + ni * 16 + l15;
                int off = row * LB + ((quad ^ ((row >> 1) & 3)) * 8);
                v8s bhf = *(const v8s*)&Bsh[off];
                v8s blf = *(const v8s*)&Bsl[off];
#pragma unroll
                for (int mi = 0; mi < 4; ++mi) {
                    acc[mi][ni] = __builtin_amdgcn_mfma_f32_16x16x32_bf16(ahf[mi], bhf, acc[mi][ni], 0, 0, 0);
                    acc[mi][ni] = __builtin_amdgcn_mfma_f32_16x16x32_bf16(ahf[mi], blf, acc[mi][ni], 0, 0, 0);
                    acc[mi][ni] = __builtin_amdgcn_mfma_f32_16x16x32_bf16(alf[mi], bhf, acc[mi][ni], 0, 0, 0);
                }
            }
        }
    }

    // ---- epilogue: bias/act + split-store hi/lo
    const size_t crow0 = (size_t)zb * cZRows + m0;
#pragma unroll
    for (int ni = 0; ni < 4; ++ni) {
        int n = n0 + wn * 64 + ni * 16 + l15;
        float bv = (ACT > 0) ? bias[n] : 0.f;
        float av = (ACT == 2) ? alpha[n] : 0.f;
#pragma unroll
        for (int mi = 0; mi < 4; ++mi) {
#pragma unroll
            for (int r = 0; r < 4; ++r) {
                int m = wm * 64 + mi * 16 + quad * 4 + r;
                float v = acc[mi][ni][r] + bv;
                if (ACT == 1) v = v > 0.f ? v : 0.f;
                if (ACT == 2) v = v > 0.f ? v : av * v;
                size_t o = (crow0 + m) * (size_t)Nout + n;
                unsigned short h = f2bf(v);
                oh[o] = h;
                ol[o] = f2bf(v - bf2f(h));
            }
        }
    }
}

// ---------------------------------------------------------------------------
__global__ __launch_bounds__(256) void final_gemm(const unsigned short* __restrict__ hh,
                                                  const unsigned short* __restrict__ hl,
                                                  const float* __restrict__ W,
                                                  const float* __restrict__ bias,
                                                  float* __restrict__ out) {
    const int t = threadIdx.x;
    const int m = blockIdx.x * 64 + (t >> 2);
    const int kq = (t & 3) * 64;
    const unsigned short* ph = hh + (size_t)m * 256 + kq;
    const unsigned short* pl = hl + (size_t)m * 256 + kq;
    float a0 = 0.f, a1 = 0.f;
#pragma unroll
    for (int i = 0; i < 8; ++i) {
        uint4 vh = *(const uint4*)(ph + i * 8);
        uint4 vl = *(const uint4*)(pl + i * 8);
        const unsigned short* sh = (const unsigned short*)&vh;
        const unsigned short* sl = (const unsigned short*)&vl;
#pragma unroll
        for (int j = 0; j < 8; ++j) {
            int k = kq + i * 8 + j;
            float h = bf2f(sh[j]) + bf2f(sl[j]);
            a0 += h * W[k * 2];
            a1 += h * W[k * 2 + 1];
        }
    }
    a0 += __shfl_down(a0, 2); a0 += __shfl_down(a0, 1);
    a1 += __shfl_down(a1, 2); a1 += __shfl_down(a1, 1);
    if ((t & 3) == 0) {
        out[(size_t)m * 2] = a0 + bias[0];
        out[(size_t)m * 2 + 1] = a1 + bias[1];
    }
}

// ---------------------------------------------------------------------------
extern "C" void kernel_launch(void* const* d_in, const int* in_sizes, int n_in,
                              void* d_out, int out_size, void* d_ws, size_t ws_size,
                              hipStream_t stream) {
    const float* x   = (const float*)d_in[0];
    const float* adj = (const float*)d_in[1];
    const float* W1  = (const float*)d_in[2];
    const float* b1  = (const float*)d_in[3];
    const float* W2  = (const float*)d_in[4];
    const float* b2  = (const float*)d_in[5];
    const float* W3  = (const float*)d_in[6];
    const float* b3  = (const float*)d_in[7];
    const float* W4  = (const float*)d_in[8];
    const float* b4  = (const float*)d_in[9];
    const float* cW1 = (const float*)d_in[10];
    const float* cb1 = (const float*)d_in[11];
    const float* alp = (const float*)d_in[12];
    const float* cW2 = (const float*)d_in[13];
    const float* cb2 = (const float*)d_in[14];
    float* out = (float*)d_out;

    const size_t P = 32768ull * 512;
    const size_t WT_TOT = 1245184;
    const size_t ADJ = 32ull * 1024 * 1024;

    unsigned short* N1h = (unsigned short*)d_ws;
    unsigned short* N1l = N1h + P;
    unsigned short* N2h = N1l + P;
    unsigned short* N2l = N2h + P;
    unsigned short* N3h = N2l + P;
    unsigned short* N3l = N3h + P;
    unsigned short* Th  = N3l + P;
    unsigned short* Tl  = Th + P;
    unsigned short* WTh = Tl + P;
    unsigned short* WTl = WTh + WT_TOT;
    unsigned short* SAh = WTl + WT_TOT;
    unsigned short* SAl = SAh + ADJ;

    const size_t o1 = 0, o2 = 262144, o3 = 786432, o4 = 1048576, o5 = 1179648;
    const bool preAdj = ws_size >= (8 * P + 2 * WT_TOT + 2 * ADJ) * sizeof(unsigned short);

    dim3 blk(256);

    split_pair<<<8192, blk, 0, stream>>>(x, N1h, N1l, (int)(32ull * 1024 * 256 / 4));
    tsplit<<<1024, blk, 0, stream>>>(W1,  WTh + o1, WTl + o1, 512, 512);
    tsplit<<<2048, blk, 0, stream>>>(W2,  WTh + o2, WTl + o2, 1024, 512);
    tsplit<<<1024, blk, 0, stream>>>(W3,  WTh + o3, WTl + o3, 1024, 256);
    tsplit<<<512,  blk, 0, stream>>>(W4,  WTh + o4, WTl + o4, 512, 256);
    tsplit<<<256,  blk, 0, stream>>>(cW1, WTh + o5, WTl + o5, 256, 256);
    if (preAdj)
        split_pair<<<32768, blk, 0, stream>>>(adj, SAh, SAl, (int)(ADJ / 4));

    // xT -> T
    transp<true><<<dim3(16, 4, 32), blk, 0, stream>>>(x, nullptr, Th, Tl, 256);
    // agg1 = adj @ x (d=256) -> N2
    if (preAdj)
        gemm128<0, false, 0><<<512, blk, 0, stream>>>(
            SAh, SAl, nullptr, nullptr, 1024, 0, Th, Tl, 1024, nullptr, nullptr,
            N2h, N2l, 256, (size_t)1 << 20, 256ull * 1024, 1024, 2, 3);
    else
        gemm128<0, false, 1><<<512, blk, 0, stream>>>(
            adj, nullptr, nullptr, nullptr, 1024, 0, Th, Tl, 1024, nullptr, nullptr,
            N2h, N2l, 256, (size_t)1 << 20, 256ull * 1024, 1024, 2, 3);
    // dense1 = relu([x|AGG1] @ W1 + b1) (N=512) -> N3
    gemm128<1, true, 0><<<1024, blk, 0, stream>>>(
        N1h, N1l, N2h, N2l, 256, 256, WTh + o1, WTl + o1, 512, b1, nullptr,
        N3h, N3l, 512, 0, 0, 0, 4, 8);
    // H1T -> T
    transp<false><<<dim3(16, 8, 32), blk, 0, stream>>>(N3h, N3l, Th, Tl, 512);
    // agg2 = adj @ H1 (d=512) -> N1
    if (preAdj)
        gemm128<0, false, 0><<<1024, blk, 0, stream>>>(
            SAh, SAl, nullptr, nullptr, 1024, 0, Th, Tl, 1024, nullptr, nullptr,
            N1h, N1l, 512, (size_t)1 << 20, 512ull * 1024, 1024, 4, 3);
    else
        gemm128<0, false, 1><<<1024, blk, 0, stream>>>(
            adj, nullptr, nullptr, nullptr, 1024, 0, Th, Tl, 1024, nullptr, nullptr,
            N1h, N1l, 512, (size_t)1 << 20, 512ull * 1024, 1024, 4, 3);
    // dense2 (N=512) -> N2
    gemm128<1, true, 0><<<1024, blk, 0, stream>>>(
        N3h, N3l, N1h, N1l, 512, 512, WTh + o2, WTl + o2, 1024, b2, nullptr,
        N2h, N2l, 512, 0, 0, 0, 4, 8);
    // H2T -> T
    transp<false><<<dim3(16, 8, 32), blk, 0, stream>>>(N2h, N2l, Th, Tl, 512);
    // agg3 = adj @ H2 (d=512) -> N1
    if (preAdj)
        gemm128<0, false, 0><<<1024, blk, 0, stream>>>(
            SAh, SAl, nullptr, nullptr, 1024, 0, Th, Tl, 1024, nullptr, nullptr,
            N1h, N1l, 512, (size_t)1 << 20, 512ull * 1024, 1024, 4, 3);
    else
        gemm128<0, false, 1><<<1024, blk, 0, stream>>>(
            adj, nullptr, nullptr, nullptr, 1024, 0, Th, Tl, 1024, nullptr, nullptr,
            N1h, N1l, 512, (size_t)1 << 20, 512ull * 1024, 1024, 4, 3);
    // dense3 (N=256) -> N3
    gemm128<1, true, 0><<<512, blk, 0, stream>>>(
        N2h, N2l, N1h, N1l, 512, 512, WTh + o3, WTl + o3, 1024, b3, nullptr,
        N3h, N3l, 256, 0, 0, 0, 2, 8);
    // H3T -> T
    transp<false><<<dim3(16, 4, 32), blk, 0, stream>>>(N3h, N3l, Th, Tl, 256);
    // agg4 = adj @ H3 (d=256) -> N1
    if (preAdj)
        gemm128<0, false, 0><<<512, blk, 0, stream>>>(
            SAh, SAl, nullptr, nullptr, 1024, 0, Th, Tl, 1024, nullptr, nullptr,
            N1h, N1l, 256, (size_t)1 << 20, 256ull * 1024, 1024, 2, 3);
    else
        gemm128<0, false, 1><<<512, blk, 0, stream>>>(
            adj, nullptr, nullptr, nullptr, 1024, 0, Th, Tl, 1024, nullptr, nullptr,
            N1h, N1l, 256, (size_t)1 << 20, 256ull * 1024, 1024, 2, 3);
    // dense4 (N=256) -> N2
    gemm128<1, true, 0><<<512, blk, 0, stream>>>(
        N3h, N3l, N1h, N1l, 256, 256, WTh + o4, WTl + o4, 512, b4, nullptr,
        N2h, N2l, 256, 0, 0, 0, 2, 8);
    // cls1 = prelu(H4 @ cW1 + cb1) (N=256) -> N3
    gemm128<2, false, 0><<<512, blk, 0, stream>>>(
        N2h, N2l, nullptr, nullptr, 256, 0, WTh + o5, WTl + o5, 256, cb1, alp,
        N3h, N3l, 256, 0, 0, 0, 2, 8);
    // final
    final_gemm<<<512, blk, 0, stream>>>(N3h, N3l, cW2, cb2, out);
}

// Round 5
// 868.740 us; speedup vs baseline: 1.4556x; 1.2626x over previous
//
#include <hip/hip_runtime.h>

typedef short v8s __attribute__((ext_vector_type(8)));
typedef float v4f __attribute__((ext_vector_type(4)));

#define BMT 128
#define BNT 128
#define BKT 32

__device__ __forceinline__ unsigned short f2bf(float f) {
    unsigned int u = __float_as_uint(f);
    u += 0x7fff + ((u >> 16) & 1);   // RNE
    return (unsigned short)(u >> 16);
}
__device__ __forceinline__ float bf2f(unsigned short h) {
    return __uint_as_float(((unsigned int)h) << 16);
}

union U128 { unsigned short s[8]; uint4 v; };

// async 16B global -> LDS (wave-uniform LDS base + lane*16 implicit)
__device__ __forceinline__ void gld16(const unsigned short* g, unsigned short* l) {
    __builtin_amdgcn_global_load_lds((const __attribute__((address_space(1))) void*)g,
                                     (__attribute__((address_space(3))) void*)l, 16, 0, 0);
}

// ---------------------------------------------------------------------------
__global__ __launch_bounds__(256) void split_pair(const float* __restrict__ x,
                                                  unsigned short* __restrict__ oh,
                                                  unsigned short* __restrict__ ol, int n4) {
    int i = blockIdx.x * 256 + threadIdx.x;
    if (i < n4) {
        float4 f = ((const float4*)x)[i];
        float fv[4] = {f.x, f.y, f.z, f.w};
        ushort4 h, l;
        unsigned short* hp = (unsigned short*)&h;
        unsigned short* lp = (unsigned short*)&l;
#pragma unroll
        for (int j = 0; j < 4; ++j) {
            unsigned short hh = f2bf(fv[j]);
            hp[j] = hh;
            lp[j] = f2bf(fv[j] - bf2f(hh));
        }
        ((ushort4*)oh)[i] = h;
        ((ushort4*)ol)[i] = l;
    }
}

// fp32 -> bf16 (hi only) — for adj (1-term agg path)
__global__ __launch_bounds__(256) void split_hi(const float* __restrict__ x,
                                                unsigned short* __restrict__ oh, int n4) {
    int i = blockIdx.x * 256 + threadIdx.x;
    if (i < n4) {
        float4 f = ((const float4*)x)[i];
        float fv[4] = {f.x, f.y, f.z, f.w};
        ushort4 h;
        unsigned short* hp = (unsigned short*)&h;
#pragma unroll
        for (int j = 0; j < 4; ++j) hp[j] = f2bf(fv[j]);
        ((ushort4*)oh)[i] = h;
    }
}

// split + transpose: W fp32 [R][C] -> WT hi/lo bf16 [C][R]
__global__ __launch_bounds__(256) void tsplit(const float* __restrict__ W,
                                              unsigned short* __restrict__ th,
                                              unsigned short* __restrict__ tl, int R, int C) {
    int e = blockIdx.x * 256 + threadIdx.x;
    if (e < R * C) {
        int k = e / C, n = e - k * C;
        float w = W[e];
        unsigned short h = f2bf(w);
        size_t o = (size_t)n * R + k;
        th[o] = h;
        tl[o] = f2bf(w - bf2f(h));
    }
}

// ---------------------------------------------------------------------------
// Transpose H [z*1024+node][d] (bf16-hi plane, or fp32 if F32) -> HT-hi [z*d+f][1024]
// 64x64 tiles, uint lanes in LDS (pad 66), coalesced both sides. hi only.
template <bool F32>
__global__ __launch_bounds__(256) void transp(const void* __restrict__ srcA,
                                              unsigned short* __restrict__ th, int d) {
    __shared__ unsigned int lds[64 * 66];
    const int t = threadIdx.x;
    const int mt = blockIdx.x, ft = blockIdx.y, z = blockIdx.z;
    const int r = t >> 3, c8 = (t & 7) * 8;
#pragma unroll
    for (int half = 0; half < 2; ++half) {
        int rr = r + half * 32;
        size_t grow = (size_t)z * 1024 + mt * 64 + rr;
        unsigned int u[8];
        if constexpr (F32) {
            const float* xs = (const float*)srcA + grow * d + ft * 64 + c8;
            float4 f0 = *(const float4*)xs;
            float4 f1 = *(const float4*)(xs + 4);
            float fv[8] = {f0.x, f0.y, f0.z, f0.w, f1.x, f1.y, f1.z, f1.w};
#pragma unroll
            for (int j = 0; j < 8; ++j) u[j] = f2bf(fv[j]);
        } else {
            const unsigned short* hp = (const unsigned short*)srcA + grow * d + ft * 64 + c8;
            U128 uh;
            uh.v = *(const uint4*)hp;
#pragma unroll
            for (int j = 0; j < 8; ++j) u[j] = uh.s[j];
        }
#pragma unroll
        for (int j = 0; j < 8; ++j)
            lds[rr * 66 + c8 + j] = u[j];
    }
    __syncthreads();
    const int f = t >> 3, m0 = (t & 7) * 8;
#pragma unroll
    for (int half = 0; half < 2; ++half) {
        int ff = f + half * 32;
        U128 uh;
#pragma unroll
        for (int j = 0; j < 8; ++j)
            uh.s[j] = (unsigned short)lds[(m0 + j) * 66 + ff];
        size_t orow = ((size_t)z * d + ft * 64 + ff) * 1024 + mt * 64 + m0;
        *(uint4*)(th + orow) = uh.v;
    }
}

// ---------------------------------------------------------------------------
// 128x128x32 split-bf16 GEMM, 1-D swizzled grid (nblk n-blocks co-located per XCD).
// AMODE: 0 = pre-split bf16 [M][K] via global_load_lds; 1 = fp32, convert in-kernel.
// B always pre-split k-contiguous [N][ldb] via global_load_lds.
// LO: true = 3-term hi/lo split math; false = 1-term bf16 (agg path, hi planes only)
// ACT: 0 none/no bias, 1 bias+relu, 2 bias+prelu
template <int ACT, bool TWO, int AMODE, bool LO>
__global__ __launch_bounds__(256) void gemm128(
    const void* a1a, const void* a1b,
    const unsigned short* __restrict__ a2h, const unsigned short* __restrict__ a2l,
    int K1, int K2,
    const unsigned short* __restrict__ bh_, const unsigned short* __restrict__ bl_, int ldb,
    const float* __restrict__ bias, const float* __restrict__ alpha,
    unsigned short* __restrict__ oh, unsigned short* __restrict__ ol, int Nout,
    size_t aZStride, size_t bZStride, int cZRows,
    int nblk, int mBits)
{
    constexpr int LA = (AMODE == 0) ? 32 : 40;
    constexpr int LB = 32;
    constexpr int NP = LO ? 2 : 1;
    __shared__ __align__(16) unsigned short Abuf[BMT * LA * NP];
    __shared__ __align__(16) unsigned short Bbuf[BNT * LB * NP];
    unsigned short* Ash = Abuf;
    unsigned short* Asl = Abuf + BMT * LA;
    unsigned short* Bsh = Bbuf;
    unsigned short* Bsl = Bbuf + BNT * LB;

    const int t = threadIdx.x;
    const int lane = t & 63, wave = t >> 6;
    const int wm = wave >> 1, wn = wave & 1;
    const int l15 = lane & 15, quad = lane >> 4;

    // swizzled decode: n-blocks sharing an A-panel land on the same XCD
    const int bx = blockIdx.x;
    const int low3 = bx & 7, rest = bx >> 3;
    const int nIdx = rest % nblk, g = rest / nblk;
    const int grp = g * 8 + low3;
    const int m0 = (grp & ((1 << mBits) - 1)) * BMT;
    const int zb = grp >> mBits;
    const int n0 = nIdx * BNT;

    const unsigned short* bhz = bh_ + (size_t)zb * bZStride;
    const unsigned short* blz = LO ? bl_ + (size_t)zb * bZStride : nullptr;

    v4f acc[4][4] = {};

    const int nch = TWO ? 2 : 1;
    for (int ch = 0; ch < nch; ++ch) {
        const int K = (TWO && ch) ? K2 : K1;
        const int kr0 = (TWO && ch) ? K1 : 0;
        const unsigned short* ah = nullptr;
        const unsigned short* al = nullptr;
        const float* af = nullptr;
        if constexpr (AMODE == 0) {
            ah = (ch ? a2h : (const unsigned short*)a1a) + (size_t)zb * aZStride;
            if constexpr (LO)
                al = (ch ? a2l : (const unsigned short*)a1b) + (size_t)zb * aZStride;
        } else {
            af = (const float*)a1a + (size_t)zb * aZStride;
        }

        for (int kk = 0; kk < K; kk += BKT) {
            __syncthreads();
            // ---- stage A
            if constexpr (AMODE == 0) {
#pragma unroll
                for (int i = 0; i < 2; ++i) {
                    int s = i * 256 + t;
                    int row = s >> 2;
                    int cg = (s & 3) ^ ((s >> 3) & 3);           // chunk swizzle
                    size_t go = (size_t)(m0 + row) * K + kk + cg * 8;
                    int ls = (i * 256 + (t & ~63)) * 8;          // wave-uniform base
                    gld16(ah + go, &Ash[ls]);
                    if constexpr (LO) gld16(al + go, &Asl[ls]);
                }
            } else {
#pragma unroll
                for (int i = 0; i < 2; ++i) {
                    int cid = i * 256 + t;
                    int row = cid >> 2, c = cid & 3;
                    const float* src = af + (size_t)(m0 + row) * K + kk + c * 8;
                    float4 f0 = *(const float4*)src;
                    float4 f1 = *(const float4*)(src + 4);
                    float fv[8] = {f0.x, f0.y, f0.z, f0.w, f1.x, f1.y, f1.z, f1.w};
                    U128 uh, ul;
#pragma unroll
                    for (int j = 0; j < 8; ++j) {
                        unsigned short h = f2bf(fv[j]);
                        uh.s[j] = h;
                        if (LO) ul.s[j] = f2bf(fv[j] - bf2f(h));
                    }
                    *(uint4*)&Ash[row * LA + c * 8] = uh.v;
                    if constexpr (LO) *(uint4*)&Asl[row * LA + c * 8] = ul.v;
                }
            }
            // ---- stage B (always gld16)
#pragma unroll
            for (int i = 0; i < 2; ++i) {
                int s = i * 256 + t;
                int row = s >> 2;
                int cg = (s & 3) ^ ((s >> 3) & 3);
                size_t go = (size_t)(n0 + row) * ldb + kr0 + kk + cg * 8;
                int ls = (i * 256 + (t & ~63)) * 8;
                gld16(bhz + go, &Bsh[ls]);
                if constexpr (LO) gld16(blz + go, &Bsl[ls]);
            }
            __syncthreads();
            // ---- compute
            v8s ahf[4], alf[4];
#pragma unroll
            for (int mi = 0; mi < 4; ++mi) {
                int row = wm * 64 + mi * 16 + l15;
                int off;
                if constexpr (AMODE == 0) off = row * LA + ((quad ^ ((row >> 1) & 3)) * 8);
                else                      off = row * LA + quad * 8;
                ahf[mi] = *(const v8s*)&Ash[off];
                if constexpr (LO) alf[mi] = *(const v8s*)&Asl[off];
            }
#pragma unroll
            for (int ni = 0; ni < 4; ++ni) {
                int row = wn * 64 + ni * 16 + l15;
                int off = row * LB + ((quad ^ ((row >> 1) & 3)) * 8);
                v8s bhf = *(const v8s*)&Bsh[off];
                v8s blf;
                if constexpr (LO) blf = *(const v8s*)&Bsl[off];
#pragma unroll
                for (int mi = 0; mi < 4; ++mi) {
                    acc[mi][ni] = __builtin_amdgcn_mfma_f32_16x16x32_bf16(ahf[mi], bhf, acc[mi][ni], 0, 0, 0);
                    if constexpr (LO) {
                        acc[mi][ni] = __builtin_amdgcn_mfma_f32_16x16x32_bf16(ahf[mi], blf, acc[mi][ni], 0, 0, 0);
                        acc[mi][ni] = __builtin_amdgcn_mfma_f32_16x16x32_bf16(alf[mi], bhf, acc[mi][ni], 0, 0, 0);
                    }
                }
            }
        }
    }

    // ---- epilogue: bias/act + split-store hi/lo
    const size_t crow0 = (size_t)zb * cZRows + m0;
#pragma unroll
    for (int ni = 0; ni < 4; ++ni) {
        int n = n0 + wn * 64 + ni * 16 + l15;
        float bv = (ACT > 0) ? bias[n] : 0.f;
        float av = (ACT == 2) ? alpha[n] : 0.f;
#pragma unroll
        for (int mi = 0; mi < 4; ++mi) {
#pragma unroll
            for (int r = 0; r < 4; ++r) {
                int m = wm * 64 + mi * 16 + quad * 4 + r;
                float v = acc[mi][ni][r] + bv;
                if (ACT == 1) v = v > 0.f ? v : 0.f;
                if (ACT == 2) v = v > 0.f ? v : av * v;
                size_t o = (crow0 + m) * (size_t)Nout + n;
                unsigned short h = f2bf(v);
                oh[o] = h;
                ol[o] = f2bf(v - bf2f(h));
            }
        }
    }
}

// ---------------------------------------------------------------------------
__global__ __launch_bounds__(256) void final_gemm(const unsigned short* __restrict__ hh,
                                                  const unsigned short* __restrict__ hl,
                                                  const float* __restrict__ W,
                                                  const float* __restrict__ bias,
                                                  float* __restrict__ out) {
    const int t = threadIdx.x;
    const int m = blockIdx.x * 64 + (t >> 2);
    const int kq = (t & 3) * 64;
    const unsigned short* ph = hh + (size_t)m * 256 + kq;
    const unsigned short* pl = hl + (size_t)m * 256 + kq;
    float a0 = 0.f, a1 = 0.f;
#pragma unroll
    for (int i = 0; i < 8; ++i) {
        uint4 vh = *(const uint4*)(ph + i * 8);
        uint4 vl = *(const uint4*)(pl + i * 8);
        const unsigned short* sh = (const unsigned short*)&vh;
        const unsigned short* sl = (const unsigned short*)&vl;
#pragma unroll
        for (int j = 0; j < 8; ++j) {
            int k = kq + i * 8 + j;
            float h = bf2f(sh[j]) + bf2f(sl[j]);
            a0 += h * W[k * 2];
            a1 += h * W[k * 2 + 1];
        }
    }
    a0 += __shfl_down(a0, 2); a0 += __shfl_down(a0, 1);
    a1 += __shfl_down(a1, 2); a1 += __shfl_down(a1, 1);
    if ((t & 3) == 0) {
        out[(size_t)m * 2] = a0 + bias[0];
        out[(size_t)m * 2 + 1] = a1 + bias[1];
    }
}

// ---------------------------------------------------------------------------
extern "C" void kernel_launch(void* const* d_in, const int* in_sizes, int n_in,
                              void* d_out, int out_size, void* d_ws, size_t ws_size,
                              hipStream_t stream) {
    const float* x   = (const float*)d_in[0];
    const float* adj = (const float*)d_in[1];
    const float* W1  = (const float*)d_in[2];
    const float* b1  = (const float*)d_in[3];
    const float* W2  = (const float*)d_in[4];
    const float* b2  = (const float*)d_in[5];
    const float* W3  = (const float*)d_in[6];
    const float* b3  = (const float*)d_in[7];
    const float* W4  = (const float*)d_in[8];
    const float* b4  = (const float*)d_in[9];
    const float* cW1 = (const float*)d_in[10];
    const float* cb1 = (const float*)d_in[11];
    const float* alp = (const float*)d_in[12];
    const float* cW2 = (const float*)d_in[13];
    const float* cb2 = (const float*)d_in[14];
    float* out = (float*)d_out;

    const size_t P = 32768ull * 512;
    const size_t WT_TOT = 1245184;
    const size_t ADJ = 32ull * 1024 * 1024;

    unsigned short* N1h = (unsigned short*)d_ws;
    unsigned short* N1l = N1h + P;
    unsigned short* N2h = N1l + P;
    unsigned short* N2l = N2h + P;
    unsigned short* N3h = N2l + P;
    unsigned short* N3l = N3h + P;
    unsigned short* Th  = N3l + P;           // transposed activations, hi only
    unsigned short* WTh = Th + P;
    unsigned short* WTl = WTh + WT_TOT;
    unsigned short* SAh = WTl + WT_TOT;      // adj bf16 hi only

    const size_t o1 = 0, o2 = 262144, o3 = 786432, o4 = 1048576, o5 = 1179648;
    const bool preAdj = ws_size >= (7 * P + 2 * WT_TOT + ADJ) * sizeof(unsigned short);

    dim3 blk(256);

    split_pair<<<8192, blk, 0, stream>>>(x, N1h, N1l, (int)(32ull * 1024 * 256 / 4));
    tsplit<<<1024, blk, 0, stream>>>(W1,  WTh + o1, WTl + o1, 512, 512);
    tsplit<<<2048, blk, 0, stream>>>(W2,  WTh + o2, WTl + o2, 1024, 512);
    tsplit<<<1024, blk, 0, stream>>>(W3,  WTh + o3, WTl + o3, 1024, 256);
    tsplit<<<512,  blk, 0, stream>>>(W4,  WTh + o4, WTl + o4, 512, 256);
    tsplit<<<256,  blk, 0, stream>>>(cW1, WTh + o5, WTl + o5, 256, 256);
    if (preAdj)
        split_hi<<<32768, blk, 0, stream>>>(adj, SAh, (int)(ADJ / 4));

    // xT (hi) -> T
    transp<true><<<dim3(16, 4, 32), blk, 0, stream>>>(x, Th, 256);
    // agg1 = adj @ x (d=256) -> N2   [1-term bf16]
    if (preAdj)
        gemm128<0, false, 0, false><<<512, blk, 0, stream>>>(
            SAh, nullptr, nullptr, nullptr, 1024, 0, Th, nullptr, 1024, nullptr, nullptr,
            N2h, N2l, 256, (size_t)1 << 20, 256ull * 1024, 1024, 2, 3);
    else
        gemm128<0, false, 1, false><<<512, blk, 0, stream>>>(
            adj, nullptr, nullptr, nullptr, 1024, 0, Th, nullptr, 1024, nullptr, nullptr,
            N2h, N2l, 256, (size_t)1 << 20, 256ull * 1024, 1024, 2, 3);
    // dense1 = relu([x|AGG1] @ W1 + b1) (N=512) -> N3
    gemm128<1, true, 0, true><<<1024, blk, 0, stream>>>(
        N1h, N1l, N2h, N2l, 256, 256, WTh + o1, WTl + o1, 512, b1, nullptr,
        N3h, N3l, 512, 0, 0, 0, 4, 8);
    // H1T (hi) -> T
    transp<false><<<dim3(16, 8, 32), blk, 0, stream>>>(N3h, Th, 512);
    // agg2 = adj @ H1 (d=512) -> N1
    if (preAdj)
        gemm128<0, false, 0, false><<<1024, blk, 0, stream>>>(
            SAh, nullptr, nullptr, nullptr, 1024, 0, Th, nullptr, 1024, nullptr, nullptr,
            N1h, N1l, 512, (size_t)1 << 20, 512ull * 1024, 1024, 4, 3);
    else
        gemm128<0, false, 1, false><<<1024, blk, 0, stream>>>(
            adj, nullptr, nullptr, nullptr, 1024, 0, Th, nullptr, 1024, nullptr, nullptr,
            N1h, N1l, 512, (size_t)1 << 20, 512ull * 1024, 1024, 4, 3);
    // dense2 (N=512) -> N2
    gemm128<1, true, 0, true><<<1024, blk, 0, stream>>>(
        N3h, N3l, N1h, N1l, 512, 512, WTh + o2, WTl + o2, 1024, b2, nullptr,
        N2h, N2l, 512, 0, 0, 0, 4, 8);
    // H2T (hi) -> T
    transp<false><<<dim3(16, 8, 32), blk, 0, stream>>>(N2h, Th, 512);
    // agg3 = adj @ H2 (d=512) -> N1
    if (preAdj)
        gemm128<0, false, 0, false><<<1024, blk, 0, stream>>>(
            SAh, nullptr, nullptr, nullptr, 1024, 0, Th, nullptr, 1024, nullptr, nullptr,
            N1h, N1l, 512, (size_t)1 << 20, 512ull * 1024, 1024, 4, 3);
    else
        gemm128<0, false, 1, false><<<1024, blk, 0, stream>>>(
            adj, nullptr, nullptr, nullptr, 1024, 0, Th, nullptr, 1024, nullptr, nullptr,
            N1h, N1l, 512, (size_t)1 << 20, 512ull * 1024, 1024, 4, 3);
    // dense3 (N=256) -> N3
    gemm128<1, true, 0, true><<<512, blk, 0, stream>>>(
        N2h, N2l, N1h, N1l, 512, 512, WTh + o3, WTl + o3, 1024, b3, nullptr,
        N3h, N3l, 256, 0, 0, 0, 2, 8);
    // H3T (hi) -> T
    transp<false><<<dim3(16, 4, 32), blk, 0, stream>>>(N3h, Th, 256);
    // agg4 = adj @ H3 (d=256) -> N1
    if (preAdj)
        gemm128<0, false, 0, false><<<512, blk, 0, stream>>>(
            SAh, nullptr, nullptr, nullptr, 1024, 0, Th, nullptr, 1024, nullptr, nullptr,
            N1h, N1l, 256, (size_t)1 << 20, 256ull * 1024, 1024, 2, 3);
    else
        gemm128<0, false, 1, false><<<512, blk, 0, stream>>>(
            adj, nullptr, nullptr, nullptr, 1024, 0, Th, nullptr, 1024, nullptr, nullptr,
            N1h, N1l, 256, (size_t)1 << 20, 256ull * 1024, 1024, 2, 3);
    // dense4 (N=256) -> N2
    gemm128<1, true, 0, true><<<512, blk, 0, stream>>>(
        N3h, N3l, N1h, N1l, 256, 256, WTh + o4, WTl + o4, 512, b4, nullptr,
        N2h, N2l, 256, 0, 0, 0, 2, 8);
    // cls1 = prelu(H4 @ cW1 + cb1) (N=256) -> N3
    gemm128<2, false, 0, true><<<512, blk, 0, stream>>>(
        N2h, N2l, nullptr, nullptr, 256, 0, WTh + o5, WTl + o5, 256, cb1, alp,
        N3h, N3l, 256, 0, 0, 0, 2, 8);
    // final
    final_gemm<<<512, blk, 0, stream>>>(N3h, N3l, cW2, cb2, out);
}

// Round 6
// 642.793 us; speedup vs baseline: 1.9672x; 1.3515x over previous
//
#include <hip/hip_runtime.h>

typedef short v8s __attribute__((ext_vector_type(8)));
typedef _Float16 v8h __attribute__((ext_vector_type(8)));
typedef float v4f __attribute__((ext_vector_type(4)));

#define BMT 128
#define BNT 128
#define BKT 32

__device__ __forceinline__ unsigned short f2bf(float f) {
    unsigned int u = __float_as_uint(f);
    u += 0x7fff + ((u >> 16) & 1);   // RNE
    return (unsigned short)(u >> 16);
}
__device__ __forceinline__ unsigned short f2h(float f) {
    union { _Float16 h; unsigned short u; } c;
    c.h = (_Float16)f;
    return c.u;
}
__device__ __forceinline__ float h2f(unsigned short v) {
    union { unsigned short u; _Float16 h; } c;
    c.u = v;
    return (float)c.h;
}
__device__ __forceinline__ v8h as_h(v8s x) {
    union { v8s s; v8h h; } c;
    c.s = x;
    return c.h;
}

union U128 { unsigned short s[8]; uint4 v; };

// async 16B global -> LDS (wave-uniform LDS base + lane*16 implicit)
__device__ __forceinline__ void gld16(const unsigned short* g, unsigned short* l) {
    __builtin_amdgcn_global_load_lds((const __attribute__((address_space(1))) void*)g,
                                     (__attribute__((address_space(3))) void*)l, 16, 0, 0);
}

// ---------------------------------------------------------------------------
// fp32 -> f16 plane
__global__ __launch_bounds__(256) void split_f16(const float* __restrict__ x,
                                                 unsigned short* __restrict__ o, int n4) {
    int i = blockIdx.x * 256 + threadIdx.x;
    if (i < n4) {
        float4 f = ((const float4*)x)[i];
        float fv[4] = {f.x, f.y, f.z, f.w};
        ushort4 h;
        unsigned short* hp = (unsigned short*)&h;
#pragma unroll
        for (int j = 0; j < 4; ++j) hp[j] = f2h(fv[j]);
        ((ushort4*)o)[i] = h;
    }
}

// fp32 -> bf16 plane (adj)
__global__ __launch_bounds__(256) void split_hi(const float* __restrict__ x,
                                                unsigned short* __restrict__ oh, int n4) {
    int i = blockIdx.x * 256 + threadIdx.x;
    if (i < n4) {
        float4 f = ((const float4*)x)[i];
        float fv[4] = {f.x, f.y, f.z, f.w};
        ushort4 h;
        unsigned short* hp = (unsigned short*)&h;
#pragma unroll
        for (int j = 0; j < 4; ++j) hp[j] = f2bf(fv[j]);
        ((ushort4*)oh)[i] = h;
    }
}

// transpose-convert: W fp32 [R][C] -> WT f16 [C][R]
__global__ __launch_bounds__(256) void tsplit16(const float* __restrict__ W,
                                                unsigned short* __restrict__ th, int R, int C) {
    int e = blockIdx.x * 256 + threadIdx.x;
    if (e < R * C) {
        int k = e / C, n = e - k * C;
        th[(size_t)n * R + k] = f2h(W[e]);
    }
}

// ---------------------------------------------------------------------------
// x fp32 [z*1024+node][d] -> xT bf16 [z*d+f][1024]   (agg1 B operand)
__global__ __launch_bounds__(256) void transp_x(const float* __restrict__ src,
                                                unsigned short* __restrict__ th, int d) {
    __shared__ unsigned int lds[64 * 66];
    const int t = threadIdx.x;
    const int mt = blockIdx.x, ft = blockIdx.y, z = blockIdx.z;
    const int r = t >> 3, c8 = (t & 7) * 8;
#pragma unroll
    for (int half = 0; half < 2; ++half) {
        int rr = r + half * 32;
        size_t grow = (size_t)z * 1024 + mt * 64 + rr;
        const float* xs = src + grow * d + ft * 64 + c8;
        float4 f0 = *(const float4*)xs;
        float4 f1 = *(const float4*)(xs + 4);
        float fv[8] = {f0.x, f0.y, f0.z, f0.w, f1.x, f1.y, f1.z, f1.w};
#pragma unroll
        for (int j = 0; j < 8; ++j)
            lds[rr * 66 + c8 + j] = f2bf(fv[j]);
    }
    __syncthreads();
    const int f = t >> 3, m0 = (t & 7) * 8;
#pragma unroll
    for (int half = 0; half < 2; ++half) {
        int ff = f + half * 32;
        U128 uh;
#pragma unroll
        for (int j = 0; j < 8; ++j)
            uh.s[j] = (unsigned short)lds[(m0 + j) * 66 + ff];
        size_t orow = ((size_t)z * d + ft * 64 + ff) * 1024 + mt * 64 + m0;
        *(uint4*)(th + orow) = uh.v;
    }
}

// ---------------------------------------------------------------------------
// 128x128x32 GEMM, 1-term MFMA, 1-D swizzled grid.
// DT: 0 = bf16 operands (agg), 1 = f16 operands (dense)
// AMODE: 0 = pre-converted plane [M][K] via global_load_lds; 1 = fp32 convert (adj fallback)
// ACT: 0 none/no bias, 1 bias+relu, 2 bias+prelu
// WRT: additionally store bf16 transposed output HT[m0>>10][Nout][1024] from acc
template <int ACT, bool TWO, int AMODE, int DT, bool WRT>
__global__ __launch_bounds__(256) void gemm128(
    const void* a1, const unsigned short* __restrict__ a2,
    int K1, int K2,
    const unsigned short* __restrict__ b_, int ldb,
    const float* __restrict__ bias, const float* __restrict__ alpha,
    unsigned short* __restrict__ o_, int Nout,
    unsigned short* __restrict__ th,
    size_t aZ, size_t bZ, int cZRows,
    int nblk, int mBits)
{
    constexpr int LA = (AMODE == 0) ? 32 : 40;
    constexpr int LB = 32;
    __shared__ __align__(16) unsigned short Ash[BMT * LA];
    __shared__ __align__(16) unsigned short Bsh[BNT * LB];

    const int t = threadIdx.x;
    const int lane = t & 63, wave = t >> 6;
    const int wm = wave >> 1, wn = wave & 1;
    const int l15 = lane & 15, quad = lane >> 4;

    // swizzled decode: n-blocks sharing an A-panel land on the same XCD
    const int bx = blockIdx.x;
    const int low3 = bx & 7, rest = bx >> 3;
    const int nIdx = rest % nblk, g = rest / nblk;
    const int grp = g * 8 + low3;
    const int m0 = (grp & ((1 << mBits) - 1)) * BMT;
    const int zb = grp >> mBits;
    const int n0 = nIdx * BNT;

    const unsigned short* bhz = b_ + (size_t)zb * bZ;

    v4f acc[4][4] = {};

    const int nch = TWO ? 2 : 1;
    for (int ch = 0; ch < nch; ++ch) {
        const int K = (TWO && ch) ? K2 : K1;
        const int kr0 = (TWO && ch) ? K1 : 0;
        const unsigned short* ah = nullptr;
        const float* af = nullptr;
        if constexpr (AMODE == 0)
            ah = (ch ? a2 : (const unsigned short*)a1) + (size_t)zb * aZ;
        else
            af = (const float*)a1 + (size_t)zb * aZ;

        for (int kk = 0; kk < K; kk += BKT) {
            __syncthreads();
            // ---- stage A
            if constexpr (AMODE == 0) {
#pragma unroll
                for (int i = 0; i < 2; ++i) {
                    int s = i * 256 + t;
                    int row = s >> 2;
                    int cg = (s & 3) ^ ((s >> 3) & 3);           // chunk swizzle
                    size_t go = (size_t)(m0 + row) * K + kk + cg * 8;
                    int ls = (i * 256 + (t & ~63)) * 8;          // wave-uniform base
                    gld16(ah + go, &Ash[ls]);
                }
            } else {
#pragma unroll
                for (int i = 0; i < 2; ++i) {
                    int cid = i * 256 + t;
                    int row = cid >> 2, c = cid & 3;
                    const float* src = af + (size_t)(m0 + row) * K + kk + c * 8;
                    float4 f0 = *(const float4*)src;
                    float4 f1 = *(const float4*)(src + 4);
                    float fv[8] = {f0.x, f0.y, f0.z, f0.w, f1.x, f1.y, f1.z, f1.w};
                    U128 uh;
#pragma unroll
                    for (int j = 0; j < 8; ++j) uh.s[j] = f2bf(fv[j]);
                    *(uint4*)&Ash[row * LA + c * 8] = uh.v;
                }
            }
            // ---- stage B
#pragma unroll
            for (int i = 0; i < 2; ++i) {
                int s = i * 256 + t;
                int row = s >> 2;
                int cg = (s & 3) ^ ((s >> 3) & 3);
                size_t go = (size_t)(n0 + row) * ldb + kr0 + kk + cg * 8;
                int ls = (i * 256 + (t & ~63)) * 8;
                gld16(bhz + go, &Bsh[ls]);
            }
            __syncthreads();
            // ---- compute
            v8s ahf[4];
#pragma unroll
            for (int mi = 0; mi < 4; ++mi) {
                int row = wm * 64 + mi * 16 + l15;
                int off;
                if constexpr (AMODE == 0) off = row * LA + ((quad ^ ((row >> 1) & 3)) * 8);
                else                      off = row * LA + quad * 8;
                ahf[mi] = *(const v8s*)&Ash[off];
            }
#pragma unroll
            for (int ni = 0; ni < 4; ++ni) {
                int row = wn * 64 + ni * 16 + l15;
                int off = row * LB + ((quad ^ ((row >> 1) & 3)) * 8);
                v8s bhf = *(const v8s*)&Bsh[off];
#pragma unroll
                for (int mi = 0; mi < 4; ++mi) {
                    if constexpr (DT == 0)
                        acc[mi][ni] = __builtin_amdgcn_mfma_f32_16x16x32_bf16(ahf[mi], bhf, acc[mi][ni], 0, 0, 0);
                    else
                        acc[mi][ni] = __builtin_amdgcn_mfma_f32_16x16x32_f16(as_h(ahf[mi]), as_h(bhf), acc[mi][ni], 0, 0, 0);
                }
            }
        }
    }

    // ---- epilogue: bias/act folded into acc, f16 normal store
    const size_t crow0 = (size_t)zb * cZRows + m0;
#pragma unroll
    for (int ni = 0; ni < 4; ++ni) {
        int n = n0 + wn * 64 + ni * 16 + l15;
        float bv = (ACT > 0) ? bias[n] : 0.f;
        float av = (ACT == 2) ? alpha[n] : 0.f;
#pragma unroll
        for (int mi = 0; mi < 4; ++mi) {
#pragma unroll
            for (int r = 0; r < 4; ++r) {
                int m = wm * 64 + mi * 16 + quad * 4 + r;
                float v = acc[mi][ni][r] + bv;
                if (ACT == 1) v = v > 0.f ? v : 0.f;
                if (ACT == 2) v = v > 0.f ? v : av * v;
                acc[mi][ni][r] = v;
                o_[(crow0 + m) * (size_t)Nout + n] = f2h(v);
            }
        }
    }

    // ---- fused transposed bf16 store: HT[zbT][f][1024], 8B chunks from acc
    if constexpr (WRT) {
        const int zbT = m0 >> 10;
        const int mloc0 = (m0 & 1023) + wm * 64;
#pragma unroll
        for (int ni = 0; ni < 4; ++ni) {
            int f = n0 + wn * 64 + ni * 16 + l15;
            size_t rowb = (((size_t)zbT * Nout + f) << 10) + mloc0;
#pragma unroll
            for (int mi = 0; mi < 4; ++mi) {
                ushort4 u;
                unsigned short* up = (unsigned short*)&u;
#pragma unroll
                for (int r = 0; r < 4; ++r) up[r] = f2bf(acc[mi][ni][r]);
                *(ushort4*)(th + rowb + mi * 16 + quad * 4) = u;
            }
        }
    }
}

// ---------------------------------------------------------------------------
// pred = H5 @ cW2 + cb2, H5 f16 single plane, fp32 accumulation
__global__ __launch_bounds__(256) void final_gemm(const unsigned short* __restrict__ hh,
                                                  const float* __restrict__ W,
                                                  const float* __restrict__ bias,
                                                  float* __restrict__ out) {
    const int t = threadIdx.x;
    const int m = blockIdx.x * 64 + (t >> 2);
    const int kq = (t & 3) * 64;
    const unsigned short* ph = hh + (size_t)m * 256 + kq;
    float a0 = 0.f, a1 = 0.f;
#pragma unroll
    for (int i = 0; i < 8; ++i) {
        uint4 vh = *(const uint4*)(ph + i * 8);
        const unsigned short* sh = (const unsigned short*)&vh;
#pragma unroll
        for (int j = 0; j < 8; ++j) {
            int k = kq + i * 8 + j;
            float h = h2f(sh[j]);
            a0 += h * W[k * 2];
            a1 += h * W[k * 2 + 1];
        }
    }
    a0 += __shfl_down(a0, 2); a0 += __shfl_down(a0, 1);
    a1 += __shfl_down(a1, 2); a1 += __shfl_down(a1, 1);
    if ((t & 3) == 0) {
        out[(size_t)m * 2] = a0 + bias[0];
        out[(size_t)m * 2 + 1] = a1 + bias[1];
    }
}

// ---------------------------------------------------------------------------
extern "C" void kernel_launch(void* const* d_in, const int* in_sizes, int n_in,
                              void* d_out, int out_size, void* d_ws, size_t ws_size,
                              hipStream_t stream) {
    const float* x   = (const float*)d_in[0];
    const float* adj = (const float*)d_in[1];
    const float* W1  = (const float*)d_in[2];
    const float* b1  = (const float*)d_in[3];
    const float* W2  = (const float*)d_in[4];
    const float* b2  = (const float*)d_in[5];
    const float* W3  = (const float*)d_in[6];
    const float* b3  = (const float*)d_in[7];
    const float* W4  = (const float*)d_in[8];
    const float* b4  = (const float*)d_in[9];
    const float* cW1 = (const float*)d_in[10];
    const float* cb1 = (const float*)d_in[11];
    const float* alp = (const float*)d_in[12];
    const float* cW2 = (const float*)d_in[13];
    const float* cb2 = (const float*)d_in[14];
    float* out = (float*)d_out;

    const size_t P   = 32768ull * 512;       // 16,777,216 ushorts per act plane
    const size_t XP  = 32768ull * 256;       // x f16 plane
    const size_t WT_TOT = 1245184;
    const size_t ADJ = 32ull * 1024 * 1024;

    unsigned short* N1  = (unsigned short*)d_ws;
    unsigned short* N2  = N1 + P;
    unsigned short* N3  = N2 + P;
    unsigned short* Th  = N3 + P;            // transposed activations, bf16
    unsigned short* X16 = Th + P;            // x as f16
    unsigned short* WT  = X16 + XP;          // transposed weights, f16
    unsigned short* SA  = WT + WT_TOT;       // adj bf16

    const size_t o1 = 0, o2 = 262144, o3 = 786432, o4 = 1048576, o5 = 1179648;
    const bool preAdj = ws_size >= (4 * P + XP + WT_TOT + ADJ) * sizeof(unsigned short);

    dim3 blk(256);

    split_f16<<<8192, blk, 0, stream>>>(x, X16, (int)(XP / 4));
    tsplit16<<<1024, blk, 0, stream>>>(W1,  WT + o1, 512, 512);
    tsplit16<<<2048, blk, 0, stream>>>(W2,  WT + o2, 1024, 512);
    tsplit16<<<1024, blk, 0, stream>>>(W3,  WT + o3, 1024, 256);
    tsplit16<<<512,  blk, 0, stream>>>(W4,  WT + o4, 512, 256);
    tsplit16<<<256,  blk, 0, stream>>>(cW1, WT + o5, 256, 256);
    if (preAdj)
        split_hi<<<32768, blk, 0, stream>>>(adj, SA, (int)(ADJ / 4));

    // xT (bf16) -> Th
    transp_x<<<dim3(16, 4, 32), blk, 0, stream>>>(x, Th, 256);
    // agg1 = adj @ x (d=256) -> N2 [bf16 1-term, f16 out]
    if (preAdj)
        gemm128<0, false, 0, 0, false><<<512, blk, 0, stream>>>(
            SA, nullptr, 1024, 0, Th, 1024, nullptr, nullptr,
            N2, 256, nullptr, (size_t)1 << 20, 256ull * 1024, 1024, 2, 3);
    else
        gemm128<0, false, 1, 0, false><<<512, blk, 0, stream>>>(
            adj, nullptr, 1024, 0, Th, 1024, nullptr, nullptr,
            N2, 256, nullptr, (size_t)1 << 20, 256ull * 1024, 1024, 2, 3);
    // dense1 = relu([x|AGG1] @ W1 + b1) (N=512) -> N3, fused H1T -> Th
    gemm128<1, true, 0, 1, true><<<1024, blk, 0, stream>>>(
        X16, N2, 256, 256, WT + o1, 512, b1, nullptr,
        N3, 512, Th, 0, 0, 0, 4, 8);
    // agg2 = adj @ H1 (d=512) -> N1
    if (preAdj)
        gemm128<0, false, 0, 0, false><<<1024, blk, 0, stream>>>(
            SA, nullptr, 1024, 0, Th, 1024, nullptr, nullptr,
            N1, 512, nullptr, (size_t)1 << 20, 512ull * 1024, 1024, 4, 3);
    else
        gemm128<0, false, 1, 0, false><<<1024, blk, 0, stream>>>(
            adj, nullptr, 1024, 0, Th, 1024, nullptr, nullptr,
            N1, 512, nullptr, (size_t)1 << 20, 512ull * 1024, 1024, 4, 3);
    // dense2 (N=512) -> N2, fused H2T -> Th
    gemm128<1, true, 0, 1, true><<<1024, blk, 0, stream>>>(
        N3, N1, 512, 512, WT + o2, 1024, b2, nullptr,
        N2, 512, Th, 0, 0, 0, 4, 8);
    // agg3 = adj @ H2 (d=512) -> N1
    if (preAdj)
        gemm128<0, false, 0, 0, false><<<1024, blk, 0, stream>>>(
            SA, nullptr, 1024, 0, Th, 1024, nullptr, nullptr,
            N1, 512, nullptr, (size_t)1 << 20, 512ull * 1024, 1024, 4, 3);
    else
        gemm128<0, false, 1, 0, false><<<1024, blk, 0, stream>>>(
            adj, nullptr, 1024, 0, Th, 1024, nullptr, nullptr,
            N1, 512, nullptr, (size_t)1 << 20, 512ull * 1024, 1024, 4, 3);
    // dense3 (N=256) -> N3, fused H3T -> Th
    gemm128<1, true, 0, 1, true><<<512, blk, 0, stream>>>(
        N2, N1, 512, 512, WT + o3, 1024, b3, nullptr,
        N3, 256, Th, 0, 0, 0, 2, 8);
    // agg4 = adj @ H3 (d=256) -> N1
    if (preAdj)
        gemm128<0, false, 0, 0, false><<<512, blk, 0, stream>>>(
            SA, nullptr, 1024, 0, Th, 1024, nullptr, nullptr,
            N1, 256, nullptr, (size_t)1 << 20, 256ull * 1024, 1024, 2, 3);
    else
        gemm128<0, false, 1, 0, false><<<512, blk, 0, stream>>>(
            adj, nullptr, 1024, 0, Th, 1024, nullptr, nullptr,
            N1, 256, nullptr, (size_t)1 << 20, 256ull * 1024, 1024, 2, 3);
    // dense4 (N=256) -> N2
    gemm128<1, true, 0, 1, false><<<512, blk, 0, stream>>>(
        N3, N1, 256, 256, WT + o4, 512, b4, nullptr,
        N2, 256, nullptr, 0, 0, 0, 2, 8);
    // cls1 = prelu(H4 @ cW1 + cb1) (N=256) -> N3
    gemm128<2, false, 0, 1, false><<<512, blk, 0, stream>>>(
        N2, nullptr, 256, 0, WT + o5, 256, cb1, alp,
        N3, 256, nullptr, 0, 0, 0, 2, 8);
    // final
    final_gemm<<<512, blk, 0, stream>>>(N3, cW2, cb2, out);
}